// Round 12
// baseline (761.517 us; speedup 1.0000x reference)
//
#include <hip/hip_runtime.h>
#include <stdint.h>

typedef int v4i  __attribute__((ext_vector_type(4)));
typedef int v16i __attribute__((ext_vector_type(16)));

#define M_TOK 8192
#define N_OUT 4096
#define K_IN  4096

#define BM 256
#define BN 256
#define BK 64                      // bytes (= i8 elems) per K-tile
#define NT (K_IN / BK)             // 64 K-tiles
#define RING_STRIDE 32768          // A 16 KiB + B 16 KiB per ring slot
#define LDS_BYTES (4 * RING_STRIDE)  // 128 KiB, ring of 4

// MFMA with the accumulator FORCED into AGPRs ("a" constraint). R11 lesson:
// at acc[4][4] = 256 regs the compiler keeps everything in v0-v255 and
// spills acc to scratch (VGPR_Count=256, +705 MB scratch traffic, 478 us).
// With "+a" the acc lives in the AGPR half of the gfx950 unified file:
// 256 AGPR + ~120 arch VGPR fits the 512-reg budget at 1 wave/SIMD.
#define MFMA_I8(accv, av, bv)                                                \
    asm volatile("v_mfma_i32_32x32x32_i8 %0, %1, %2, %0"                     \
                 : "+a"(accv) : "v"(av), "v"(bv))

// -------------------------------------------------------------------------
// Pack both int32-carrier tensors into int8 in one dispatch. (~38 us,
// BW-bound: 240 MB @ ~6.3 TB/s)
// -------------------------------------------------------------------------
__device__ __forceinline__ int pack4(int4 a) {
    return (a.x & 255) | ((a.y & 255) << 8) | ((a.z & 255) << 16) | ((a.w & 255) << 24);
}

__global__ __launch_bounds__(256) void pack_both(
    const int4* __restrict__ x, const int4* __restrict__ w,
    int* __restrict__ dA, int* __restrict__ dB, int n4x, int n4w)
{
    int i = blockIdx.x * blockDim.x + threadIdx.x;
    if (i < n4x) {
        dA[i] = pack4(x[i]);
    } else {
        int j = i - n4x;
        if (j < n4w) dB[j] = pack4(w[j]);
    }
}

// -------------------------------------------------------------------------
// i8 GEMM, R12 = R11 geometry (verified correct: passed, absmax 0) with
// the AGPR fix. 256x256 block, 4 waves, wave = 128x128 as 4x4 frags of
// mfma_i32_32x32x32_i8. Rationale (6-round evidence): per-K-tile time ==
// MFMA(1171 cyc) + LDS demand, the serial sum, under every schedule; the
// only lever the wall responds to is SHRINKING the LDS term. 128x64 wave
// tiles: 96 KB reads/tile (0.75 reads/MFMA); 128x128: 64 KB (0.5) ->
// LDS demand 1536 -> ~1030 cyc, floor ~2200 cyc/tile = ~117 us gemm with
// zero overlap assumed. 1 wave/SIMD: in-wave R/M slack (36 cyc MFMA issue
// stall each) hides the 16 reads under the 32-MFMA cluster.
// R8 skeleton: ring-4, 1 barrier/tile, counted vmcnt(16) (8 gloads/wave/
// tile, 2 tiles in flight), branch-free clamped dead-slot prefetch.
// SQ_LDS_BANK_CONFLICT = 4.0/ds_read_b128 floor (invariant across all
// variants; R9 all-VMEM = 0 proved attribution) -- not actionable.
// -------------------------------------------------------------------------
__global__ __launch_bounds__(256, 1) void gemm_i8_kernel(
    const char* __restrict__ A8,      // [M][K] int8 row-major
    const char* __restrict__ B8,      // [N][K] int8 row-major
    const float* __restrict__ scale_ptr,
    float* __restrict__ out)          // [M][N] float + 1 scalar at end
{
    extern __shared__ char lds[];     // 4 ring slots: [A 16K | B 16K] each

    const int tid  = threadIdx.x;
    const int wave = tid >> 6;        // 0..3
    const int lane = tid & 63;

    // ---- bijective XCD swizzle of the 512-block grid (512 % 8 == 0).
    int wg = (blockIdx.x & 7) * 64 + (blockIdx.x >> 3);
    const int bx = wg >> 5;           // 0..15 (N tiles)
    const int by = wg & 31;           // 0..31 (M tiles)
    const int bm = by * BM;
    const int bn = bx * BN;

    const int wm = (wave >> 1) * 128; // wave row offset in tile
    const int wn = (wave & 1) * 128;  // wave col offset in tile

    v16i acc[4][4];
#pragma unroll
    for (int mi = 0; mi < 4; ++mi)
#pragma unroll
        for (int nj = 0; nj < 4; ++nj)
#pragma unroll
            for (int r = 0; r < 16; ++r)
                acc[mi][nj][r] = 0;

    // ---- staging geometry: wave-load = 64 lanes x 16 B = 16 rows of 64 B.
    // Wave stages A rows [wave*64, +64) and B rows [wave*64, +64): 4+4
    // gloads per tile. Source granule pre-swizzled (gload_lds dest is
    // linear lane*16): f(row) = ((row>>1)&3) ^ ((row>>3)&3), row = r0+srow,
    // r0 = wave*64 + q*16 -> row bit4 = q&1.
    const int srow  = lane >> 2;                                  // 0..15
    const int fbase = ((srow >> 1) & 3) ^ ((srow >> 3) & 1);

    const char* gA[4]; const char* gB[4];
    int ldsAoff[4], ldsBoff[4];
#pragma unroll
    for (int q = 0; q < 4; ++q) {
        const int r0  = wave * 64 + q * 16;
        const int sgr = (lane & 3) ^ fbase ^ ((q & 1) << 1);
        gA[q] = A8 + (size_t)(bm + r0 + srow) * K_IN + sgr * 16;
        gB[q] = B8 + (size_t)(bn + r0 + srow) * K_IN + sgr * 16;
        ldsAoff[q] = r0 * 64;              // A at slot offset 0
        ldsBoff[q] = 16384 + r0 * 64;      // B at slot offset 16 KiB
    }

    // ISSUE_*: dest slot (tile)&3; source K clamped (dest slot is dead when
    // tile >= NT; staging stale data there is harmless; keeps body
    // branch-free and the vmcnt count uniform).
#define ISSUE_A(tile) do {                                                   \
        char* _rb = lds + ((tile) & 3) * RING_STRIDE;                        \
        const int _k0 = (((tile) < NT) ? (tile) : (NT - 1)) * BK;            \
        _Pragma("unroll")                                                    \
        for (int _q = 0; _q < 4; ++_q)                                       \
            __builtin_amdgcn_global_load_lds(                                \
                (const __attribute__((address_space(1))) void*)(gA[_q]+_k0), \
                (__attribute__((address_space(3))) void*)(_rb+ldsAoff[_q]),  \
                16, 0, 0);                                                   \
    } while (0)
#define ISSUE_B(tile) do {                                                   \
        char* _rb = lds + ((tile) & 3) * RING_STRIDE;                        \
        const int _k0 = (((tile) < NT) ? (tile) : (NT - 1)) * BK;            \
        _Pragma("unroll")                                                    \
        for (int _q = 0; _q < 4; ++_q)                                       \
            __builtin_amdgcn_global_load_lds(                                \
                (const __attribute__((address_space(1))) void*)(gB[_q]+_k0), \
                (__attribute__((address_space(3))) void*)(_rb+ldsBoff[_q]),  \
                16, 0, 0);                                                   \
    } while (0)

    // ---- fragment geometry (32x32x32 i8): lane reads 16 B of row fm at
    // global granule g = kk*2 + fh; stored LDS granule = g ^ f(row);
    // row bits 1-4 == fm bits 1-4 (bases are multiples of 32).
    const int fm  = lane & 31;
    const int fh  = lane >> 5;                          // 0/1
    const int fsw = ((fm >> 1) & 3) ^ ((fm >> 3) & 3);  // f(row)
    const int g0  = ((0 + fh) ^ fsw) << 4;              // kk=0 byte offset
    const int g1  = ((2 + fh) ^ fsw) << 4;              // kk=1 byte offset
    const int abase = (wm + fm) * 64;                   // + mi*2048
    const int bbase = 16384 + (wn + fm) * 64;           // + nj*2048

    // ---- prologue: tiles 0,1,2 in flight (24 gloads/wave)
    ISSUE_A(0); ISSUE_B(0);
    ISSUE_A(1); ISSUE_B(1);
    ISSUE_A(2); ISSUE_B(2);
    asm volatile("s_waitcnt vmcnt(16)" ::: "memory");   // tile 0 landed
    __builtin_amdgcn_s_barrier();

    // set0 <- (tile 0, phase 0)
    v4i a0[4], b0[4], a1[4], b1[4];
#pragma unroll
    for (int mi = 0; mi < 4; ++mi)
        a0[mi] = *(const v4i*)(lds + abase + mi * 2048 + g0);
#pragma unroll
    for (int nj = 0; nj < 4; ++nj)
        b0[nj] = *(const v4i*)(lds + bbase + nj * 2048 + g0);

    for (int t = 0; t < NT; ++t) {
        char* rb = lds + (t & 3) * RING_STRIDE;
        char* rn = lds + ((t + 1) & 3) * RING_STRIDE;

        // ======== phase A: reads (t,ph1)->set1, A-stage, MFMA set0 =======
#pragma unroll
        for (int mi = 0; mi < 4; ++mi)
            a1[mi] = *(const v4i*)(rb + abase + mi * 2048 + g1);
#pragma unroll
        for (int nj = 0; nj < 4; ++nj)
            b1[nj] = *(const v4i*)(rb + bbase + nj * 2048 + g1);
        ISSUE_A(t + 3);
#pragma unroll
        for (int mi = 0; mi < 4; ++mi)
#pragma unroll
            for (int nj = 0; nj < 4; ++nj)
                MFMA_I8(acc[mi][nj], a0[mi], b0[nj]);

        // ---- tile boundary: B-stage, counted vmcnt (never 0) + barrier.
        // Outstanding after ISSUE_B: tiles t+2 (8) + t+3 (8) = 16 ->
        // vmcnt(16) guarantees t+1 fully landed for this wave; every wave
        // does the same before the barrier.
        ISSUE_B(t + 3);
        asm volatile("s_waitcnt vmcnt(16)" ::: "memory");
        __builtin_amdgcn_s_barrier();

        // ======== phase B: reads (t+1,ph0)->set0, MFMA set1 ==============
        // (at t = NT-1 the reads hit a stale slot; values feed nothing)
#pragma unroll
        for (int mi = 0; mi < 4; ++mi)
            a0[mi] = *(const v4i*)(rn + abase + mi * 2048 + g0);
#pragma unroll
        for (int nj = 0; nj < 4; ++nj)
            b0[nj] = *(const v4i*)(rn + bbase + nj * 2048 + g0);
#pragma unroll
        for (int mi = 0; mi < 4; ++mi)
#pragma unroll
            for (int nj = 0; nj < 4; ++nj)
                MFMA_I8(acc[mi][nj], a1[mi], b1[nj]);
    }
#undef ISSUE_A
#undef ISSUE_B

    // ---- epilogue: y = clip(rint(acc * scale), -128, 127) as float
    // 32x32 C/D layout: col = lane&31, row = (reg&3) + 8*(reg>>2) + 4*(lane>>5)
    const float s     = scale_ptr[0];
    const float scale = (s * 0.1f) / 0.1f;   // match ref op order

#pragma unroll
    for (int mi = 0; mi < 4; ++mi) {
#pragma unroll
        for (int nj = 0; nj < 4; ++nj) {
#pragma unroll
            for (int r = 0; r < 16; ++r) {
                int row = bm + wm + mi * 32 + (r & 3) + 8 * (r >> 2) + 4 * fh;
                int col = bn + wn + nj * 32 + fm;
                float y = (float)acc[mi][nj][r] * scale;
                y = rintf(y);
                y = fminf(fmaxf(y, -128.0f), 127.0f);
                out[(size_t)row * N_OUT + col] = y;
            }
        }
    }

    if (bm == 0 && bn == 0 && tid == 0)
        out[(size_t)M_TOK * N_OUT] = 0.1f;
}

// -------------------------------------------------------------------------
extern "C" void kernel_launch(void* const* d_in, const int* in_sizes, int n_in,
                              void* d_out, int out_size, void* d_ws, size_t ws_size,
                              hipStream_t stream)
{
    const int*   x_q     = (const int*)d_in[0];   // [8192*4096] int32 carriers
    const int*   w_q     = (const int*)d_in[1];   // [4096*4096] int32 carriers
    const float* scale_x = (const float*)d_in[2]; // 1 element
    float* out = (float*)d_out;

    char* A8 = (char*)d_ws;                              // 32 MB
    char* B8 = (char*)d_ws + (size_t)M_TOK * K_IN;       // 16 MB

    const int n4x = (M_TOK * K_IN) / 4;   // 8388608
    const int n4w = (N_OUT * K_IN) / 4;   // 4194304

    // one-time: allow 128 KiB dynamic LDS (host-side attribute, not a
    // stream op -> graph-capture safe)
    static bool once = []{
        hipFuncSetAttribute(reinterpret_cast<const void*>(gemm_i8_kernel),
                            hipFuncAttributeMaxDynamicSharedMemorySize,
                            LDS_BYTES);
        return true;
    }();
    (void)once;

    pack_both<<<(n4x + n4w) / 256, 256, 0, stream>>>(
        (const int4*)x_q, (const int4*)w_q, (int*)A8, (int*)B8, n4x, n4w);

    // 512 blocks (16 N-tiles x 32 M-tiles), 256 threads, 128 KiB LDS
    gemm_i8_kernel<<<512, 256, LDS_BYTES, stream>>>(A8, B8, scale_x, out);
}

// Round 13
// 553.751 us; speedup vs baseline: 1.3752x; 1.3752x over previous
//
#include <hip/hip_runtime.h>
#include <stdint.h>

typedef int v4i  __attribute__((ext_vector_type(4)));
typedef int v16i __attribute__((ext_vector_type(16)));

#define M_TOK 8192
#define N_OUT 4096
#define K_IN  4096

#define BM 256
#define BN 256
#define BK 64                      // bytes (= i8 elems) per K-tile
#define NT (K_IN / BK)             // 64 K-tiles
#define RING_STRIDE 32768          // A 16 KiB + B 16 KiB per ring slot
#define LDS_BYTES (4 * RING_STRIDE)  // 128 KiB, ring of 4

// MFMA with the accumulator FORCED into AGPRs ("+a"). R12 proved this path
// functionally correct (absmax 0) and moved acc to AGPRs, but ~20 arch
// VGPRs still spilled: the 2-deep fragment pipeline's second set (32 regs)
// pushed the arch half over. R13 drops to ONE fragment set (in-wave
// pipelining measured worth ~0 in R5/R8 anyway): arch ~100 + AGPR 256
// fits 512 unified with slack at 1 wave/SIMD.
#define MFMA_I8(accv, av, bv)                                                \
    asm volatile("v_mfma_i32_32x32x32_i8 %0, %1, %2, %0"                     \
                 : "+a"(accv) : "v"(av), "v"(bv))

// -------------------------------------------------------------------------
// Pack both int32-carrier tensors into int8 in one dispatch. (~38 us,
// BW-bound: 240 MB @ ~6.3 TB/s)
// -------------------------------------------------------------------------
__device__ __forceinline__ int pack4(int4 a) {
    return (a.x & 255) | ((a.y & 255) << 8) | ((a.z & 255) << 16) | ((a.w & 255) << 24);
}

__global__ __launch_bounds__(256) void pack_both(
    const int4* __restrict__ x, const int4* __restrict__ w,
    int* __restrict__ dA, int* __restrict__ dB, int n4x, int n4w)
{
    int i = blockIdx.x * blockDim.x + threadIdx.x;
    if (i < n4x) {
        dA[i] = pack4(x[i]);
    } else {
        int j = i - n4x;
        if (j < n4w) dB[j] = pack4(w[j]);
    }
}

// -------------------------------------------------------------------------
// i8 GEMM, R13: 256x256 block, 4 waves, wave = 128x128 as 4x4 frags of
// mfma_i32_32x32x32_i8, acc in AGPRs via "+a" inline asm, SINGLE fragment
// set (kk-sequential). Rationale (8-round evidence): per-K-tile time ==
// MFMA + LDS demand (serial sum) under every schedule; only SHRINKING the
// LDS term moves the wall. 128x128 wave tiles: reads 64 KB/block-tile
// (vs 96 for 128x64) -> floor ~= 1165 (MFMA) + ~1150 (LDS) ~= 2320
// cyc/tile ~= 122 us gemm with zero overlap assumed.
// R11 lesson: builtin at acc=256 regs -> compiler spills acc (478 us).
// R12 lesson: "+a" works but 2 frag sets overflow arch half by ~20 regs
// (544 us). R13: one frag set. Gate counter: VGPR_Count <= ~140 and
// WRITE_SIZE == 131 MB means allocation finally clean.
// R8 skeleton: ring-4, 1 barrier/tile, counted vmcnt(16) (8 gloads/wave/
// tile, 2 tiles in flight), branch-free clamped dead-slot prefetch.
// SQ_LDS_BANK_CONFLICT = 4.0/ds_read_b128 floor (invariant; R9 all-VMEM
// = 0 proved attribution) -- not actionable.
// -------------------------------------------------------------------------
__global__ __launch_bounds__(256, 1) void gemm_i8_kernel(
    const char* __restrict__ A8,      // [M][K] int8 row-major
    const char* __restrict__ B8,      // [N][K] int8 row-major
    const float* __restrict__ scale_ptr,
    float* __restrict__ out)          // [M][N] float + 1 scalar at end
{
    extern __shared__ char lds[];     // 4 ring slots: [A 16K | B 16K] each

    const int tid  = threadIdx.x;
    const int wave = tid >> 6;        // 0..3
    const int lane = tid & 63;

    // ---- bijective XCD swizzle of the 512-block grid (512 % 8 == 0).
    int wg = (blockIdx.x & 7) * 64 + (blockIdx.x >> 3);
    const int bx = wg >> 5;           // 0..15 (N tiles)
    const int by = wg & 31;           // 0..31 (M tiles)
    const int bm = by * BM;
    const int bn = bx * BN;

    const int wm = (wave >> 1) * 128; // wave row offset in tile
    const int wn = (wave & 1) * 128;  // wave col offset in tile

    v16i acc[4][4];
#pragma unroll
    for (int mi = 0; mi < 4; ++mi)
#pragma unroll
        for (int nj = 0; nj < 4; ++nj)
#pragma unroll
            for (int r = 0; r < 16; ++r)
                acc[mi][nj][r] = 0;

    // ---- staging geometry: wave-load = 64 lanes x 16 B = 16 rows of 64 B.
    // Wave stages A rows [wave*64, +64) and B rows [wave*64, +64): 4+4
    // gloads per tile. Source granule pre-swizzled (gload_lds dest is
    // linear lane*16): f(row) = ((row>>1)&3) ^ ((row>>3)&3), row = r0+srow,
    // r0 = wave*64 + q*16 -> row bit4 = q&1.
    const int srow  = lane >> 2;                                  // 0..15
    const int fbase = ((srow >> 1) & 3) ^ ((srow >> 3) & 1);

    const char* gA[4]; const char* gB[4];
    int ldsAoff[4], ldsBoff[4];
#pragma unroll
    for (int q = 0; q < 4; ++q) {
        const int r0  = wave * 64 + q * 16;
        const int sgr = (lane & 3) ^ fbase ^ ((q & 1) << 1);
        gA[q] = A8 + (size_t)(bm + r0 + srow) * K_IN + sgr * 16;
        gB[q] = B8 + (size_t)(bn + r0 + srow) * K_IN + sgr * 16;
        ldsAoff[q] = r0 * 64;              // A at slot offset 0
        ldsBoff[q] = 16384 + r0 * 64;      // B at slot offset 16 KiB
    }

    // ISSUE_*: dest slot (tile)&3; source K clamped (dest slot is dead when
    // tile >= NT; staging stale data there is harmless; keeps body
    // branch-free and the vmcnt count uniform).
#define ISSUE_A(tile) do {                                                   \
        char* _rb = lds + ((tile) & 3) * RING_STRIDE;                        \
        const int _k0 = (((tile) < NT) ? (tile) : (NT - 1)) * BK;            \
        _Pragma("unroll")                                                    \
        for (int _q = 0; _q < 4; ++_q)                                       \
            __builtin_amdgcn_global_load_lds(                                \
                (const __attribute__((address_space(1))) void*)(gA[_q]+_k0), \
                (__attribute__((address_space(3))) void*)(_rb+ldsAoff[_q]),  \
                16, 0, 0);                                                   \
    } while (0)
#define ISSUE_B(tile) do {                                                   \
        char* _rb = lds + ((tile) & 3) * RING_STRIDE;                        \
        const int _k0 = (((tile) < NT) ? (tile) : (NT - 1)) * BK;            \
        _Pragma("unroll")                                                    \
        for (int _q = 0; _q < 4; ++_q)                                       \
            __builtin_amdgcn_global_load_lds(                                \
                (const __attribute__((address_space(1))) void*)(gB[_q]+_k0), \
                (__attribute__((address_space(3))) void*)(_rb+ldsBoff[_q]),  \
                16, 0, 0);                                                   \
    } while (0)

    // ---- fragment geometry (32x32x32 i8): lane reads 16 B of row fm at
    // global granule g = kk*2 + fh; stored LDS granule = g ^ f(row);
    // row bits 1-4 == fm bits 1-4 (bases are multiples of 32).
    const int fm  = lane & 31;
    const int fh  = lane >> 5;                          // 0/1
    const int fsw = ((fm >> 1) & 3) ^ ((fm >> 3) & 3);  // f(row)
    const int g0  = ((0 + fh) ^ fsw) << 4;              // kk=0 byte offset
    const int g1  = ((2 + fh) ^ fsw) << 4;              // kk=1 byte offset
    const int abase = (wm + fm) * 64;                   // + mi*2048
    const int bbase = 16384 + (wn + fm) * 64;           // + nj*2048

    // ---- prologue: tiles 0,1,2 in flight (24 gloads/wave)
    ISSUE_A(0); ISSUE_B(0);
    ISSUE_A(1); ISSUE_B(1);
    ISSUE_A(2); ISSUE_B(2);
    asm volatile("s_waitcnt vmcnt(16)" ::: "memory");   // tile 0 landed
    __builtin_amdgcn_s_barrier();

    v4i af[4], bf[4];                  // single fragment set (32 arch regs)

    for (int t = 0; t < NT; ++t) {
        char* rb = lds + (t & 3) * RING_STRIDE;

        // ---- kk = 0: 8 reads, A-prefetch, 16 MFMA
#pragma unroll
        for (int mi = 0; mi < 4; ++mi)
            af[mi] = *(const v4i*)(rb + abase + mi * 2048 + g0);
#pragma unroll
        for (int nj = 0; nj < 4; ++nj)
            bf[nj] = *(const v4i*)(rb + bbase + nj * 2048 + g0);
        ISSUE_A(t + 3);
#pragma unroll
        for (int mi = 0; mi < 4; ++mi)
#pragma unroll
            for (int nj = 0; nj < 4; ++nj)
                MFMA_I8(acc[mi][nj], af[mi], bf[nj]);

        // ---- kk = 1: 8 reads, B-prefetch, 16 MFMA
#pragma unroll
        for (int mi = 0; mi < 4; ++mi)
            af[mi] = *(const v4i*)(rb + abase + mi * 2048 + g1);
#pragma unroll
        for (int nj = 0; nj < 4; ++nj)
            bf[nj] = *(const v4i*)(rb + bbase + nj * 2048 + g1);
        ISSUE_B(t + 3);
#pragma unroll
        for (int mi = 0; mi < 4; ++mi)
#pragma unroll
            for (int nj = 0; nj < 4; ++nj)
                MFMA_I8(acc[mi][nj], af[mi], bf[nj]);

        // ---- tile boundary: counted vmcnt (never 0 mid-loop) + barrier.
        // Outstanding after ISSUE_B: tiles t+2 (8) + t+3 (8) = 16 ->
        // vmcnt(16) guarantees t+1 fully landed for this wave.
        asm volatile("s_waitcnt vmcnt(16)" ::: "memory");
        __builtin_amdgcn_s_barrier();
    }
#undef ISSUE_A
#undef ISSUE_B

    // ---- epilogue: y = clip(rint(acc * scale), -128, 127) as float
    // 32x32 C/D layout: col = lane&31, row = (reg&3) + 8*(reg>>2) + 4*(lane>>5)
    const float s     = scale_ptr[0];
    const float scale = (s * 0.1f) / 0.1f;   // match ref op order

#pragma unroll
    for (int mi = 0; mi < 4; ++mi) {
#pragma unroll
        for (int nj = 0; nj < 4; ++nj) {
#pragma unroll
            for (int r = 0; r < 16; ++r) {
                int row = bm + wm + mi * 32 + (r & 3) + 8 * (r >> 2) + 4 * fh;
                int col = bn + wn + nj * 32 + fm;
                float y = (float)acc[mi][nj][r] * scale;
                y = rintf(y);
                y = fminf(fmaxf(y, -128.0f), 127.0f);
                out[(size_t)row * N_OUT + col] = y;
            }
        }
    }

    if (bm == 0 && bn == 0 && tid == 0)
        out[(size_t)M_TOK * N_OUT] = 0.1f;
}

// -------------------------------------------------------------------------
extern "C" void kernel_launch(void* const* d_in, const int* in_sizes, int n_in,
                              void* d_out, int out_size, void* d_ws, size_t ws_size,
                              hipStream_t stream)
{
    const int*   x_q     = (const int*)d_in[0];   // [8192*4096] int32 carriers
    const int*   w_q     = (const int*)d_in[1];   // [4096*4096] int32 carriers
    const float* scale_x = (const float*)d_in[2]; // 1 element
    float* out = (float*)d_out;

    char* A8 = (char*)d_ws;                              // 32 MB
    char* B8 = (char*)d_ws + (size_t)M_TOK * K_IN;       // 16 MB

    const int n4x = (M_TOK * K_IN) / 4;   // 8388608
    const int n4w = (N_OUT * K_IN) / 4;   // 4194304

    // one-time: allow 128 KiB dynamic LDS (host-side attribute, not a
    // stream op -> graph-capture safe)
    static bool once = []{
        hipFuncSetAttribute(reinterpret_cast<const void*>(gemm_i8_kernel),
                            hipFuncAttributeMaxDynamicSharedMemorySize,
                            LDS_BYTES);
        return true;
    }();
    (void)once;

    pack_both<<<(n4x + n4w) / 256, 256, 0, stream>>>(
        (const int4*)x_q, (const int4*)w_q, (int*)A8, (int*)B8, n4x, n4w);

    // 512 blocks (16 N-tiles x 32 M-tiles), 256 threads, 128 KiB LDS
    gemm_i8_kernel<<<512, 256, LDS_BYTES, stream>>>(A8, B8, scale_x, out);
}

// Round 14
// 391.590 us; speedup vs baseline: 1.9447x; 1.4141x over previous
//
#include <hip/hip_runtime.h>
#include <stdint.h>

typedef int v4i  __attribute__((ext_vector_type(4)));
typedef int v16i __attribute__((ext_vector_type(16)));

#define M_TOK 8192
#define N_OUT 4096
#define K_IN  4096

#define BM 256
#define BN 256
#define BK 64                      // bytes (= i8 elems) per K-tile
#define NT (K_IN / BK)             // 64 K-tiles
#define RING_STRIDE 32768          // A 16 KiB + B 16 KiB per ring slot
#define LDS_BYTES (4 * RING_STRIDE)  // 128 KiB, ring of 4 (depth-2 prefetch)

// sched_group_barrier masks (LLVM SchedGroupMask, verified m137)
#define SGB __builtin_amdgcn_sched_group_barrier
#define SG_MFMA 0x8
#define SG_VMEM 0x20
#define SG_DSRD 0x100

// -------------------------------------------------------------------------
// Pack both int32-carrier tensors into int8 in one dispatch. (~38 us,
// BW-bound: 240 MB @ ~6.3 TB/s -- at the copy roofline.)
// -------------------------------------------------------------------------
__device__ __forceinline__ int pack4(int4 a) {
    return (a.x & 255) | ((a.y & 255) << 8) | ((a.z & 255) << 16) | ((a.w & 255) << 24);
}

__global__ __launch_bounds__(256) void pack_both(
    const int4* __restrict__ x, const int4* __restrict__ w,
    int* __restrict__ dA, int* __restrict__ dB, int n4x, int n4w)
{
    int i = blockIdx.x * blockDim.x + threadIdx.x;
    if (i < n4x) {
        dA[i] = pack4(x[i]);
    } else {
        int j = i - n4x;
        if (j < n4w) dB[j] = pack4(w[j]);
    }
}

// -------------------------------------------------------------------------
// i8 GEMM -- FINAL (R8 structure, best measured: gemm 142 us, MfmaUtil
// 47.8%, total 392 us). 256x256 tile, BK=64, 8 waves (2Mx4N), wave =
// 128x64 as 4x2 of mfma_i32_32x32x32_i8 (acc[4][2]=128 regs, placed in
// AGPRs by the compiler; arch VGPR_Count ~100, no spill). Ring-4 LDS
// (128 KiB), global_load_lds staging with source-side XOR swizzle,
// counted vmcnt(8) + ONE barrier per K-tile, 1:1 DS_READ/MFMA
// sched_group_barrier interleave.
//
// SESSION EVIDENCE (why this is the keeper):
// - Per-K-tile time == MFMA demand (1171 cyc) + LDS demand (~1500 cyc)
//   as a SERIAL SUM, invariant across 6 schedule structures: 4-barrier
//   lockstep (R1/R2, 167/164 us), 1-barrier (R3, 145), cross-phase reg
//   pipeline (R5, 145), 2-blocks/CU (R6 spilled; R7 clean, 200),
//   SGB interleave (R8, 142), split-pipe A-LDS/B-global (R10, 204).
// - All-VMEM no-LDS (R9, 233 us) proved SQ_LDS_BANK_CONFLICT (=4.0 per
//   ds_read_b128, ~1.26e7 here) is the gload write-burst + read floor,
//   not a fixable conflict: it went to exactly 0 with LDS removed.
// - The only lower-traffic geometry (128x128 wave tiles, 96->64 KB
//   reads/tile) needs acc[4][4]=256 AGPRs = the ENTIRE AGPR half; with
//   zero AGPRs free for arch-VGPR overflow, the allocator spills to
//   scratch under builtin (R11, 478 us), "+a" 2-set (R12, 544), and
//   "+a" 1-set (R13, 322). Path closed at HIP-source level.
// Remaining headroom (~120 us gemm at the serial-sum floor of the
// smaller-traffic geometry) requires hand-asm register allocation.
// -------------------------------------------------------------------------
__global__ __launch_bounds__(512, 2) void gemm_i8_kernel(
    const char* __restrict__ A8,      // [M][K] int8 row-major
    const char* __restrict__ B8,      // [N][K] int8 row-major
    const float* __restrict__ scale_ptr,
    float* __restrict__ out)          // [M][N] float + 1 scalar at end
{
    extern __shared__ char lds[];     // 4 ring slots: [A 16K | B 16K] each

    const int tid  = threadIdx.x;
    const int wave = tid >> 6;        // 0..7
    const int lane = tid & 63;

    // ---- bijective XCD swizzle of the 512-block grid (512 % 8 == 0).
    int wg = (blockIdx.x & 7) * 64 + (blockIdx.x >> 3);
    const int bx = wg >> 5;           // 0..15 (N tiles)
    const int by = wg & 31;           // 0..31 (M tiles)
    const int bm = by * BM;
    const int bn = bx * BN;

    const int wr = wave >> 2;         // 0..1
    const int wc = wave & 3;          // 0..3
    const int wm = wr * 128;          // wave row offset in tile
    const int wn = wc * 64;           // wave col offset in tile

    v16i acc[4][2];
#pragma unroll
    for (int mi = 0; mi < 4; ++mi)
#pragma unroll
        for (int nj = 0; nj < 2; ++nj)
#pragma unroll
            for (int r = 0; r < 16; ++r)
                acc[mi][nj][r] = 0;

    // ---- staging geometry: wave-load = 64 lanes x 16 B = 16 rows of 64 B.
    // Wave stages rows [wave*32, wave*32+32) of A and of B (2 loads each).
    // Source granule pre-swizzled (gload_lds dest is linear lane*16):
    // f(row) = ((row>>1)&3) ^ ((row>>3)&3), row = r0 + srow.
    const int srow = lane >> 2;                                   // 0..15

    const char* gA[2]; const char* gB[2];
    int ldsAoff[2], ldsBoff[2];
#pragma unroll
    for (int q = 0; q < 2; ++q) {
        const int r0  = wave * 32 + q * 16;
        const int f   = ((srow >> 1) & 3) ^ ((srow >> 3) & 1) ^ (q << 1);
        const int sgr = (lane & 3) ^ f;                // swizzled src granule
        gA[q] = A8 + (size_t)(bm + r0 + srow) * K_IN + sgr * 16;
        gB[q] = B8 + (size_t)(bn + r0 + srow) * K_IN + sgr * 16;
        ldsAoff[q] = r0 * 64;              // A at slot offset 0
        ldsBoff[q] = 16384 + r0 * 64;      // B at slot offset 16 KiB
    }

    // ISSUE: dest slot from (tile)&3, source K clamped to a valid tile.
    // For tile >= NT the dest slot is dead (never read again), so staging
    // stale data there is harmless; keeps the loop body branch-free.
#define ISSUE(tile, q) do {                                                  \
        char* _rb = lds + ((tile) & 3) * RING_STRIDE;                        \
        const int _src = ((tile) < NT) ? (tile) : (NT - 1);                  \
        const int _k0 = _src * BK;                                           \
        __builtin_amdgcn_global_load_lds(                                    \
            (const __attribute__((address_space(1))) void*)(gA[q] + _k0),    \
            (__attribute__((address_space(3))) void*)(_rb + ldsAoff[q]),     \
            16, 0, 0);                                                       \
        __builtin_amdgcn_global_load_lds(                                    \
            (const __attribute__((address_space(1))) void*)(gB[q] + _k0),    \
            (__attribute__((address_space(3))) void*)(_rb + ldsBoff[q]),     \
            16, 0, 0);                                                       \
    } while (0)

    // ---- fragment geometry (32x32x32 i8): lane reads 16 B of row fm at
    // global granule g = kk*2 + fh; stored LDS granule = g ^ f(row).
    const int fm  = lane & 31;
    const int fh  = lane >> 5;                          // 0/1
    const int fsw = ((fm >> 1) & 3) ^ ((fm >> 3) & 3);  // f(row)
    const int g0  = ((0 + fh) ^ fsw) << 4;              // kk=0 byte offset
    const int g1  = ((2 + fh) ^ fsw) << 4;              // kk=1 byte offset
    const int abase = (wm + fm) * 64;                   // + mi*2048
    const int bbase = 16384 + (wn + fm) * 64;           // + nj*2048

    // ---- prologue: tiles 0,1,2 in flight (12 issues/wave)
    ISSUE(0, 0); ISSUE(0, 1);
    ISSUE(1, 0); ISSUE(1, 1);
    ISSUE(2, 0); ISSUE(2, 1);
    asm volatile("s_waitcnt vmcnt(8)" ::: "memory");   // tile 0 landed
    __builtin_amdgcn_s_barrier();

    // set0 <- (tile 0, phase 0)
    v4i a0[4], b0[2], a1[4], b1[2];
#pragma unroll
    for (int mi = 0; mi < 4; ++mi)
        a0[mi] = *(const v4i*)(lds + abase + mi * 2048 + g0);
#pragma unroll
    for (int nj = 0; nj < 2; ++nj)
        b0[nj] = *(const v4i*)(lds + bbase + nj * 2048 + g0);

    for (int t = 0; t < NT; ++t) {
        char* rb = lds + (t & 3) * RING_STRIDE;
        char* rn = lds + ((t + 1) & 3) * RING_STRIDE;

        // ======== phase A: reads (t,ph1)->set1, 2 gloads, MFMA set0 ======
#pragma unroll
        for (int mi = 0; mi < 4; ++mi)
            a1[mi] = *(const v4i*)(rb + abase + mi * 2048 + g1);
#pragma unroll
        for (int nj = 0; nj < 2; ++nj)
            b1[nj] = *(const v4i*)(rb + bbase + nj * 2048 + g1);
        ISSUE(t + 3, 0);
#pragma unroll
        for (int mi = 0; mi < 4; ++mi)
#pragma unroll
            for (int nj = 0; nj < 2; ++nj)
                acc[mi][nj] = __builtin_amdgcn_mfma_i32_32x32x32_i8(
                    a0[mi], b0[nj], acc[mi][nj], 0, 0, 0);
        // interleave: R,M x6 then V,M x2 -- each MFMA-issue stall absorbs
        // one LDS/VMEM issue so the LDS pipe streams under the matrix pipe.
        SGB(SG_DSRD, 1, 0); SGB(SG_MFMA, 1, 0);
        SGB(SG_DSRD, 1, 0); SGB(SG_MFMA, 1, 0);
        SGB(SG_DSRD, 1, 0); SGB(SG_MFMA, 1, 0);
        SGB(SG_DSRD, 1, 0); SGB(SG_MFMA, 1, 0);
        SGB(SG_DSRD, 1, 0); SGB(SG_MFMA, 1, 0);
        SGB(SG_DSRD, 1, 0); SGB(SG_MFMA, 1, 0);
        SGB(SG_VMEM, 1, 0); SGB(SG_MFMA, 1, 0);
        SGB(SG_VMEM, 1, 0); SGB(SG_MFMA, 1, 0);

        // ---- tile boundary: counted vmcnt (never 0) + ONE barrier
        ISSUE(t + 3, 1);
        asm volatile("s_waitcnt vmcnt(8)" ::: "memory");
        __builtin_amdgcn_s_barrier();

        // ======== phase B: reads (t+1,ph0)->set0, MFMA set1 ==============
        // (at t = NT-1 the reads hit a stale slot; values feed nothing)
#pragma unroll
        for (int mi = 0; mi < 4; ++mi)
            a0[mi] = *(const v4i*)(rn + abase + mi * 2048 + g0);
#pragma unroll
        for (int nj = 0; nj < 2; ++nj)
            b0[nj] = *(const v4i*)(rn + bbase + nj * 2048 + g0);
#pragma unroll
        for (int mi = 0; mi < 4; ++mi)
#pragma unroll
            for (int nj = 0; nj < 2; ++nj)
                acc[mi][nj] = __builtin_amdgcn_mfma_i32_32x32x32_i8(
                    a1[mi], b1[nj], acc[mi][nj], 0, 0, 0);
        SGB(SG_DSRD, 1, 0); SGB(SG_MFMA, 1, 0);
        SGB(SG_DSRD, 1, 0); SGB(SG_MFMA, 1, 0);
        SGB(SG_DSRD, 1, 0); SGB(SG_MFMA, 1, 0);
        SGB(SG_DSRD, 1, 0); SGB(SG_MFMA, 1, 0);
        SGB(SG_DSRD, 1, 0); SGB(SG_MFMA, 1, 0);
        SGB(SG_DSRD, 1, 0); SGB(SG_MFMA, 1, 0);
        SGB(SG_MFMA, 2, 0);
    }
#undef ISSUE

    // ---- epilogue: y = clip(rint(acc * scale), -128, 127) as float
    // 32x32 C/D layout: col = lane&31, row = (reg&3) + 8*(reg>>2) + 4*(lane>>5)
    const float s     = scale_ptr[0];
    const float scale = (s * 0.1f) / 0.1f;   // match ref op order

#pragma unroll
    for (int mi = 0; mi < 4; ++mi) {
#pragma unroll
        for (int nj = 0; nj < 2; ++nj) {
#pragma unroll
            for (int r = 0; r < 16; ++r) {
                int row = bm + wm + mi * 32 + (r & 3) + 8 * (r >> 2) + 4 * fh;
                int col = bn + wn + nj * 32 + fm;
                float y = (float)acc[mi][nj][r] * scale;
                y = rintf(y);
                y = fminf(fmaxf(y, -128.0f), 127.0f);
                out[(size_t)row * N_OUT + col] = y;
            }
        }
    }

    if (bm == 0 && bn == 0 && tid == 0)
        out[(size_t)M_TOK * N_OUT] = 0.1f;
}

// -------------------------------------------------------------------------
extern "C" void kernel_launch(void* const* d_in, const int* in_sizes, int n_in,
                              void* d_out, int out_size, void* d_ws, size_t ws_size,
                              hipStream_t stream)
{
    const int*   x_q     = (const int*)d_in[0];   // [8192*4096] int32 carriers
    const int*   w_q     = (const int*)d_in[1];   // [4096*4096] int32 carriers
    const float* scale_x = (const float*)d_in[2]; // 1 element
    float* out = (float*)d_out;

    char* A8 = (char*)d_ws;                              // 32 MB
    char* B8 = (char*)d_ws + (size_t)M_TOK * K_IN;       // 16 MB

    const int n4x = (M_TOK * K_IN) / 4;   // 8388608
    const int n4w = (N_OUT * K_IN) / 4;   // 4194304

    // one-time: allow 128 KiB dynamic LDS (host-side attribute, not a
    // stream op -> graph-capture safe)
    static bool once = []{
        hipFuncSetAttribute(reinterpret_cast<const void*>(gemm_i8_kernel),
                            hipFuncAttributeMaxDynamicSharedMemorySize,
                            LDS_BYTES);
        return true;
    }();
    (void)once;

    pack_both<<<(n4x + n4w) / 256, 256, 0, stream>>>(
        (const int4*)x_q, (const int4*)w_q, (int*)A8, (int*)B8, n4x, n4w);

    // 512 blocks (16 N-tiles x 32 M-tiles), 512 threads, 128 KiB LDS
    gemm_i8_kernel<<<512, 512, LDS_BYTES, stream>>>(A8, B8, scale_x, out);
}